// Round 2
// baseline (870.011 us; speedup 1.0000x reference)
//
#include <hip/hip_runtime.h>

#define N_ROWS 65536
#define K_CB   1024
#define D_DIM  256

// ws layout (bytes)
#define OFF_WN     0        // float[1024]    np-exact ||w_k||^2 (fp32 pairwise)
#define OFF_RN     4096     // float[65536]   np-exact ||x_n||^2 (fp32 pairwise)
#define OFF_FIXCNT 266240   // int            fixup count
#define OFF_HIST   266496   // int[1024]      histogram
#define OFF_IDX    270592   // int[65536]     argmin indices
#define OFF_LIST   532736   // int[65536]     fixup row list
#define OFF_PART   794880   // double[4096]   loss partials

#define BM 128
#define BN 128
#define BI 32
#define LDS_STRIDE 132
#define TAU 1.5e-4f   // ~5 fp32 buckets at ulp(256); covers our <=1-bucket dot error

// ---- exact emulation of numpy pairwise fp32 sum of squares, n=128 block ----
// numpy: r[j]=a[j]; for i=8..120 step 8: r[j]+=a[i+j]; ((r0+r1)+(r2+r3))+((r4+r5)+(r6+r7))
__device__ __forceinline__ float pw128_sq(const float4* p) {
#pragma clang fp contract(off)
    float4 q0 = p[0], q1 = p[1];
    float r0 = q0.x * q0.x, r1 = q0.y * q0.y, r2 = q0.z * q0.z, r3 = q0.w * q0.w;
    float r4 = q1.x * q1.x, r5 = q1.y * q1.y, r6 = q1.z * q1.z, r7 = q1.w * q1.w;
    for (int i = 1; i < 16; ++i) {
        float4 u0 = p[2 * i], u1 = p[2 * i + 1];
        r0 = r0 + u0.x * u0.x; r1 = r1 + u0.y * u0.y;
        r2 = r2 + u0.z * u0.z; r3 = r3 + u0.w * u0.w;
        r4 = r4 + u1.x * u1.x; r5 = r5 + u1.y * u1.y;
        r6 = r6 + u1.z * u1.z; r7 = r7 + u1.w * u1.w;
    }
    return ((r0 + r1) + (r2 + r3)) + ((r4 + r5) + (r6 + r7));
}

__device__ __forceinline__ float rownorm_np(const float* row) {
#pragma clang fp contract(off)
    float s0 = pw128_sq((const float4*)row);
    float s1 = pw128_sq((const float4*)(row + 128));
    return s0 + s1;   // numpy recursion: n=256 -> pw(0..127) + pw(128..255)
}

// d = (A - 2*M) + C with exact fp32 op order (np: tmp=2.0*M; A-tmp; +C)
__device__ __forceinline__ float np_dist(float A, float m, float Ck) {
#pragma clang fp contract(off)
    float Bv = 2.0f * m;   // exact
    float t  = A - Bv;     // round @ ulp(~256)
    return t + Ck;         // round
}

// ---------------- K0: np-exact squared norms, one thread per row ----------------
__global__ void k_norms(const float* __restrict__ g, float* __restrict__ outp, int nrows) {
    int row = blockIdx.x * blockDim.x + threadIdx.x;
    if (row < nrows) outp[row] = rownorm_np(g + (size_t)row * D_DIM);
}

// ---------------- K2: tiled fp32 GEMM + per-row top-2 over np-bucketed d ----------------
__global__ __launch_bounds__(256) void k_dist(
        const float* __restrict__ eg, const float* __restrict__ wg,
        const float* __restrict__ rn, const float* __restrict__ wn,
        int* __restrict__ idx_ws, int* __restrict__ fixlist, int* __restrict__ fixcnt) {
    __shared__ __align__(16) float Asl[BI * LDS_STRIDE];
    __shared__ __align__(16) float Bsl[BI * LDS_STRIDE];
    const int tid = threadIdx.x;
    const int tx = tid & 15, ty = tid >> 4;
    const int rowBase = blockIdx.x * BM;

    float rA[8];
    #pragma unroll
    for (int r = 0; r < 8; ++r)
        rA[r] = rn[rowBase + ty * 4 + ((r >> 2) << 6) + (r & 3)];

    float best[8], second[8];
    int bidx[8];
    #pragma unroll
    for (int r = 0; r < 8; ++r) { best[r] = 3.4e38f; second[r] = 3.4e38f; bidx[r] = 0; }

    for (int kt = 0; kt < K_CB / BN; ++kt) {
        float acc[8][8];
        #pragma unroll
        for (int r = 0; r < 8; ++r)
            #pragma unroll
            for (int c = 0; c < 8; ++c) acc[r][c] = 0.0f;

        for (int ic = 0; ic < D_DIM / BI; ++ic) {
            __syncthreads();
            #pragma unroll
            for (int j = 0; j < 4; ++j) {
                int v   = tid + j * 256;
                int row = v >> 3;
                int i4  = v & 7;
                const float4 a4 = *(const float4*)(eg + (size_t)(rowBase + row) * D_DIM + ic * BI + i4 * 4);
                const float4 b4 = *(const float4*)(wg + (size_t)(kt * BN + row) * D_DIM + ic * BI + i4 * 4);
                int base = (i4 * 4) * LDS_STRIDE + row;
                Asl[base                 ] = a4.x;
                Asl[base +     LDS_STRIDE] = a4.y;
                Asl[base + 2 * LDS_STRIDE] = a4.z;
                Asl[base + 3 * LDS_STRIDE] = a4.w;
                Bsl[base                 ] = b4.x;
                Bsl[base +     LDS_STRIDE] = b4.y;
                Bsl[base + 2 * LDS_STRIDE] = b4.z;
                Bsl[base + 3 * LDS_STRIDE] = b4.w;
            }
            __syncthreads();
            for (int i = 0; i < BI; ++i) {
                float a[8], b[8];
                const float* Ai = &Asl[i * LDS_STRIDE];
                const float* Bi = &Bsl[i * LDS_STRIDE];
                *(float4*)&a[0] = *(const float4*)(Ai + ty * 4);
                *(float4*)&a[4] = *(const float4*)(Ai + 64 + ty * 4);
                *(float4*)&b[0] = *(const float4*)(Bi + tx * 4);
                *(float4*)&b[4] = *(const float4*)(Bi + 64 + tx * 4);
                #pragma unroll
                for (int r = 0; r < 8; ++r)
                    #pragma unroll
                    for (int c = 0; c < 8; ++c)
                        acc[r][c] = fmaf(a[r], b[c], acc[r][c]);
            }
        }
        // fold np-bucketed d into running top-2 (k ascends within thread -> first-min)
        #pragma unroll
        for (int c = 0; c < 8; ++c) {
            int k = kt * BN + tx * 4 + ((c >> 2) << 6) + (c & 3);
            float Ck = wn[k];
            #pragma unroll
            for (int r = 0; r < 8; ++r) {
                float d = np_dist(rA[r], acc[r][c], Ck);
                if (d < best[r])        { second[r] = best[r]; best[r] = d; bidx[r] = k; }
                else if (d < second[r]) { second[r] = d; }
            }
        }
    }
    // butterfly top-2 merge across 16 lanes sharing rows (same ty), lowest-index on tie
    #pragma unroll
    for (int r = 0; r < 8; ++r) {
        float b = best[r], s = second[r];
        int ix = bidx[r];
        #pragma unroll
        for (int m = 1; m < 16; m <<= 1) {
            float bo = __shfl_xor(b, m, 64);
            float so = __shfl_xor(s, m, 64);
            int   io = __shfl_xor(ix, m, 64);
            float ns = fminf(fminf(s, so), fmaxf(b, bo));
            if (bo < b || (bo == b && io < ix)) { b = bo; ix = io; }
            s = ns;
        }
        if (tx == 0) {
            int row = rowBase + ty * 4 + ((r >> 2) << 6) + (r & 3);
            idx_ws[row] = ix;
            if (s - b < TAU) {
                int p = atomicAdd(fixcnt, 1);
                fixlist[p] = row;
            }
        }
    }
}

// ---------------- K3: exact np-fp32 emulation recheck for flagged rows ----------------
__global__ void k_fixup(const float* __restrict__ eg, const float* __restrict__ wg,
                        const float* __restrict__ rn, const float* __restrict__ wn,
                        const int* __restrict__ fixlist, const int* __restrict__ fixcnt,
                        int* __restrict__ idx_ws) {
    __shared__ double xs[D_DIM];
    __shared__ float  redv[256];
    __shared__ int    redi[256];
    const int tid = threadIdx.x;
    const int cnt = *fixcnt;
    for (int j = blockIdx.x; j < cnt; j += gridDim.x) {
        int row = fixlist[j];
        __syncthreads();
        xs[tid] = (double)eg[(size_t)row * D_DIM + tid];
        __syncthreads();
        float An = rn[row];
        float bestv = 3.4e38f;
        int besti = 0;
        #pragma unroll
        for (int kk = 0; kk < 4; ++kk) {
            int k = tid + kk * 256;      // ascending within thread
            const float4* wr = (const float4*)(wg + (size_t)k * D_DIM);
            double s = 0.0;
            for (int i = 0; i < D_DIM / 4; ++i) {
                float4 f = wr[i];
                s += xs[4*i+0] * (double)f.x + xs[4*i+1] * (double)f.y
                   + xs[4*i+2] * (double)f.z + xs[4*i+3] * (double)f.w;
            }
            float m32 = (float)s;        // proxy for BLAS fp32 matmul entry
            float d = np_dist(An, m32, wn[k]);
            if (d < bestv) { bestv = d; besti = k; }
        }
        redv[tid] = bestv; redi[tid] = besti;
        __syncthreads();
        for (int st = 128; st > 0; st >>= 1) {
            if (tid < st) {
                float ov = redv[tid + st]; int oi = redi[tid + st];
                if (ov < redv[tid] || (ov == redv[tid] && oi < redi[tid])) {
                    redv[tid] = ov; redi[tid] = oi;
                }
            }
            __syncthreads();
        }
        if (tid == 0) idx_ws[row] = redi[0];
    }
}

// ---------------- K4: gather + STE output + loss partials + histogram ----------------
__global__ void k_final(const float* __restrict__ eg, const float* __restrict__ wg,
                        const int* __restrict__ idx_ws, float* __restrict__ qout,
                        float* __restrict__ iout, int* __restrict__ hist,
                        double* __restrict__ partials) {
    const int tid = threadIdx.x;
    const int rowBase = blockIdx.x * 16;
    double acc = 0.0;
    for (int rr = 0; rr < 16; ++rr) {
        int row = rowBase + rr;
        int k = idx_ws[row];
        size_t off = (size_t)row * D_DIM + tid;
        float ev = eg[off];
        float wv = wg[(size_t)k * D_DIM + tid];
        float diff = wv - ev;
        qout[off] = ev + diff;           // STE value == q, with np's (e + (q-e)) rounding
        acc += (double)(diff * diff);
        if (tid == 0) {
            iout[row] = (float)k;
            atomicAdd(&hist[k], 1);
        }
    }
    __shared__ double red[256];
    red[tid] = acc;
    __syncthreads();
    for (int st = 128; st > 0; st >>= 1) {
        if (tid < st) red[tid] += red[tid + st];
        __syncthreads();
    }
    if (tid == 0) partials[blockIdx.x] = red[0];
}

// ---------------- K5: scalars ----------------
__global__ void k_scalars(const int* __restrict__ hist, const double* __restrict__ partials,
                          float* __restrict__ sout) {
    const int tid = threadIdx.x;
    double s = 0.0;
    for (int j = tid; j < N_ROWS / 16; j += 256) s += partials[j];
    int m = 0;
    for (int j = tid; j < K_CB; j += 256) m = max(m, hist[j]);
    __shared__ double rs[256];
    __shared__ int    rm[256];
    rs[tid] = s; rm[tid] = m;
    __syncthreads();
    for (int st = 128; st > 0; st >>= 1) {
        if (tid < st) { rs[tid] += rs[tid + st]; rm[tid] = max(rm[tid], rm[tid + st]); }
        __syncthreads();
    }
    if (tid == 0) {
        sout[0] = (float)(rs[0] / (double)((size_t)N_ROWS * D_DIM));
        sout[1] = (float)rm[0] / 65536.0f;
    }
}

extern "C" void kernel_launch(void* const* d_in, const int* in_sizes, int n_in,
                              void* d_out, int out_size, void* d_ws, size_t ws_size,
                              hipStream_t stream) {
    const float* e = (const float*)d_in[0];
    const float* w = (const float*)d_in[1];
    float* out  = (float*)d_out;
    float* qout = out;
    float* iout = out + (size_t)N_ROWS * D_DIM;
    float* sout = iout + N_ROWS;

    char* ws = (char*)d_ws;
    float*  wn       = (float*) (ws + OFF_WN);
    float*  rn       = (float*) (ws + OFF_RN);
    int*    fixcnt   = (int*)   (ws + OFF_FIXCNT);
    int*    hist     = (int*)   (ws + OFF_HIST);
    int*    idxp     = (int*)   (ws + OFF_IDX);
    int*    list     = (int*)   (ws + OFF_LIST);
    double* partials = (double*)(ws + OFF_PART);

    hipMemsetAsync(ws + OFF_FIXCNT, 0, 4352, stream);   // fixcnt + hist

    hipLaunchKernelGGL(k_norms,   dim3(K_CB / 256),   dim3(256), 0, stream, w, wn, K_CB);
    hipLaunchKernelGGL(k_norms,   dim3(N_ROWS / 256), dim3(256), 0, stream, e, rn, N_ROWS);
    hipLaunchKernelGGL(k_dist,    dim3(N_ROWS / BM),  dim3(256), 0, stream, e, w, rn, wn, idxp, list, fixcnt);
    hipLaunchKernelGGL(k_fixup,   dim3(512),          dim3(256), 0, stream, e, w, rn, wn, list, fixcnt, idxp);
    hipLaunchKernelGGL(k_final,   dim3(N_ROWS / 16),  dim3(256), 0, stream, e, w, idxp, qout, iout, hist, partials);
    hipLaunchKernelGGL(k_scalars, dim3(1),            dim3(256), 0, stream, hist, partials, sout);
}

// Round 4
// 616.473 us; speedup vs baseline: 1.4113x; 1.4113x over previous
//
#include <hip/hip_runtime.h>

typedef __attribute__((ext_vector_type(8))) short short8;
typedef __attribute__((ext_vector_type(4))) float floatx4;

#define N_ROWS 65536
#define K_CB   1024
#define D_DIM  256

// ws layout (bytes)
#define OFF_RN     0         // float[65536]  np-exact ||x||^2
#define OFF_WN     262144    // float[1024]   np-exact ||w||^2
#define OFF_FIXCNT 266240    // int
#define OFF_HIST   266496    // int[1024]
#define OFF_IDX    270592    // int[65536]
#define OFF_LIST   532736    // int[65536]
#define OFF_PART   794880    // double[4096]

#define TAU 1.5e-4f
#define LDK 40               // LDS k-stride (32 + 8 pad): 16B-aligned rows, <=2-way conflicts

// ---- numpy pairwise fp32 sum-of-squares emulation (contract off!) ----
__device__ __forceinline__ float pw128_sq(const float4* p) {
#pragma clang fp contract(off)
    float4 q0 = p[0], q1 = p[1];
    float r0 = q0.x * q0.x, r1 = q0.y * q0.y, r2 = q0.z * q0.z, r3 = q0.w * q0.w;
    float r4 = q1.x * q1.x, r5 = q1.y * q1.y, r6 = q1.z * q1.z, r7 = q1.w * q1.w;
    for (int i = 1; i < 16; ++i) {
        float4 u0 = p[2 * i], u1 = p[2 * i + 1];
        r0 = r0 + u0.x * u0.x; r1 = r1 + u0.y * u0.y;
        r2 = r2 + u0.z * u0.z; r3 = r3 + u0.w * u0.w;
        r4 = r4 + u1.x * u1.x; r5 = r5 + u1.y * u1.y;
        r6 = r6 + u1.z * u1.z; r7 = r7 + u1.w * u1.w;
    }
    return ((r0 + r1) + (r2 + r3)) + ((r4 + r5) + (r6 + r7));
}
__device__ __forceinline__ float rownorm_np(const float* row) {
#pragma clang fp contract(off)
    float s0 = pw128_sq((const float4*)row);
    float s1 = pw128_sq((const float4*)(row + 128));
    return s0 + s1;
}
__device__ __forceinline__ float np_dist(float A, float m, float Ck) {
#pragma clang fp contract(off)
    float Bv = 2.0f * m;
    float t  = A - Bv;
    return t + Ck;
}

// RNE float->bf16 split helpers
__device__ __forceinline__ unsigned short bf16_rne(float x) {
    unsigned u = __float_as_uint(x);
    unsigned r = u + 0x7fff + ((u >> 16) & 1);
    return (unsigned short)(r >> 16);
}
__device__ __forceinline__ float bf16_tof(unsigned short h) {
    return __uint_as_float(((unsigned)h) << 16);
}

// ---------------- norms ----------------
__global__ void k_norms(const float* __restrict__ g, float* __restrict__ outp, int nrows) {
    int row = blockIdx.x * blockDim.x + threadIdx.x;
    if (row < nrows) outp[row] = rownorm_np(g + (size_t)row * D_DIM);
}

// ---------------- MFMA split-3 distance + per-(block,wave-half) top-2 ----------------
// grid (8, 512): x = code-block (128 codes), y = row-block (128 rows)
// partial slot = blockIdx.x*2 + wc  (16 slots, each covering codes [slot*64, slot*64+64))
__global__ __launch_bounds__(256) void k_dist(
        const float* __restrict__ eg, const float* __restrict__ wg,
        const float* __restrict__ rn, const float* __restrict__ wnorm,
        float* __restrict__ pbest, float* __restrict__ psec, int* __restrict__ pidx) {
    __shared__ __align__(16) unsigned short Ah[128 * LDK];
    __shared__ __align__(16) unsigned short Al[128 * LDK];
    __shared__ __align__(16) unsigned short Bh[128 * LDK];
    __shared__ __align__(16) unsigned short Bl[128 * LDK];

    const int tid  = threadIdx.x;
    const int lane = tid & 63;
    const int wv   = tid >> 6;
    const int q    = lane >> 4;
    const int m15  = lane & 15;
    const int wm   = wv & 1;       // wave row half
    const int wc   = wv >> 1;      // wave col half
    const int rowBase = blockIdx.y * 128;
    const int colBase = blockIdx.x * 128;

    floatx4 acc[4][4];
    #pragma unroll
    for (int mt = 0; mt < 4; ++mt)
        #pragma unroll
        for (int nt = 0; nt < 4; ++nt)
            acc[mt][nt] = (floatx4){0.f, 0.f, 0.f, 0.f};

    // staging map: thread t handles 16 consecutive elems (1 row, half a k-line)
    const int srow = tid >> 1;          // 0..127
    const int skb  = (tid & 1) * 16;    // 0 or 16 (element offset in k)

    for (int ic = 0; ic < 8; ++ic) {
        __syncthreads();
        {
            const float4* ga = (const float4*)(eg + (size_t)(rowBase + srow) * D_DIM + ic * 32 + skb);
            const float4* gb = (const float4*)(wg + (size_t)(colBase + srow) * D_DIM + ic * 32 + skb);
            float4 a0 = ga[0], a1 = ga[1], a2 = ga[2], a3 = ga[3];
            float4 b0 = gb[0], b1 = gb[1], b2 = gb[2], b3 = gb[3];
            unsigned short hbuf[16], lbuf[16];
            const float av[16] = {a0.x,a0.y,a0.z,a0.w, a1.x,a1.y,a1.z,a1.w,
                                  a2.x,a2.y,a2.z,a2.w, a3.x,a3.y,a3.z,a3.w};
            #pragma unroll
            for (int i = 0; i < 16; ++i) {
                unsigned short h = bf16_rne(av[i]);
                hbuf[i] = h;
                lbuf[i] = bf16_rne(av[i] - bf16_tof(h));
            }
            int base = srow * LDK + skb;
            *(short8*)&Ah[base] = *(short8*)&hbuf[0];
            *(short8*)&Ah[base + 8] = *(short8*)&hbuf[8];
            *(short8*)&Al[base] = *(short8*)&lbuf[0];
            *(short8*)&Al[base + 8] = *(short8*)&lbuf[8];
            const float bv[16] = {b0.x,b0.y,b0.z,b0.w, b1.x,b1.y,b1.z,b1.w,
                                  b2.x,b2.y,b2.z,b2.w, b3.x,b3.y,b3.z,b3.w};
            #pragma unroll
            for (int i = 0; i < 16; ++i) {
                unsigned short h = bf16_rne(bv[i]);
                hbuf[i] = h;
                lbuf[i] = bf16_rne(bv[i] - bf16_tof(h));
            }
            *(short8*)&Bh[base] = *(short8*)&hbuf[0];
            *(short8*)&Bh[base + 8] = *(short8*)&hbuf[8];
            *(short8*)&Bl[base] = *(short8*)&lbuf[0];
            *(short8*)&Bl[base + 8] = *(short8*)&lbuf[8];
        }
        __syncthreads();

        short8 afh[4], afl[4];
        #pragma unroll
        for (int mt = 0; mt < 4; ++mt) {
            int off = (wm * 64 + mt * 16 + m15) * LDK + q * 8;
            afh[mt] = *(short8*)&Ah[off];
            afl[mt] = *(short8*)&Al[off];
        }
        #pragma unroll
        for (int nt = 0; nt < 4; ++nt) {
            int off = (wc * 64 + nt * 16 + m15) * LDK + q * 8;
            short8 bfh = *(short8*)&Bh[off];
            short8 bfl = *(short8*)&Bl[off];
            #pragma unroll
            for (int mt = 0; mt < 4; ++mt) {
                acc[mt][nt] = __builtin_amdgcn_mfma_f32_16x16x32_bf16(afh[mt], bfh, acc[mt][nt], 0, 0, 0);
                acc[mt][nt] = __builtin_amdgcn_mfma_f32_16x16x32_bf16(afh[mt], bfl, acc[mt][nt], 0, 0, 0);
                acc[mt][nt] = __builtin_amdgcn_mfma_f32_16x16x32_bf16(afl[mt], bfh, acc[mt][nt], 0, 0, 0);
            }
        }
    }

    // epilogue: d = np_dist(A, dot, C), per-row top-2 within this wave's 64-code half
    float wnv[4];
    #pragma unroll
    for (int nt = 0; nt < 4; ++nt)
        wnv[nt] = wnorm[colBase + wc * 64 + nt * 16 + m15];

    const int slot = blockIdx.x * 2 + wc;   // 16 slots, codes [slot*64, slot*64+64)
    #pragma unroll
    for (int mt = 0; mt < 4; ++mt) {
        #pragma unroll
        for (int r = 0; r < 4; ++r) {
            int rowL = wm * 64 + mt * 16 + q * 4 + r;
            float A = rn[rowBase + rowL];
            float b = 3.4e38f, s = 3.4e38f;
            int ix = 0;
            #pragma unroll
            for (int nt = 0; nt < 4; ++nt) {
                float d = np_dist(A, acc[mt][nt][r], wnv[nt]);
                int k = colBase + wc * 64 + nt * 16 + m15;
                if (d < b)      { s = b; b = d; ix = k; }
                else if (d < s) { s = d; }
            }
            #pragma unroll
            for (int m = 1; m < 16; m <<= 1) {
                float bo = __shfl_xor(b, m, 64);
                float so = __shfl_xor(s, m, 64);
                int   io = __shfl_xor(ix, m, 64);
                float ns = fminf(fminf(s, so), fmaxf(b, bo));
                if (bo < b || (bo == b && io < ix)) { b = bo; ix = io; }
                s = ns;
            }
            if (m15 == 0) {
                int row = rowBase + rowL;
                pbest[slot * N_ROWS + row] = b;
                psec [slot * N_ROWS + row] = s;
                pidx [slot * N_ROWS + row] = ix;
            }
        }
    }
}

// ---------------- merge 16 per-slot partials, TAU flagging ----------------
__global__ void k_merge(const float* __restrict__ pbest, const float* __restrict__ psec,
                        const int* __restrict__ pidx, int* __restrict__ idx_ws,
                        int* __restrict__ fixlist, int* __restrict__ fixcnt) {
    int row = blockIdx.x * blockDim.x + threadIdx.x;
    float b = 3.4e38f, s = 3.4e38f;
    int ix = 0;
    for (int nb = 0; nb < 16; ++nb) {         // ascending k -> strict < keeps lowest idx
        float bo = pbest[nb * N_ROWS + row];
        float so = psec [nb * N_ROWS + row];
        int   io = pidx [nb * N_ROWS + row];
        if (bo < b) { s = fminf(b, so); b = bo; ix = io; }
        else        { s = fminf(s, bo); }
    }
    idx_ws[row] = ix;
    if (s - b < TAU) {
        int p = atomicAdd(fixcnt, 1);
        fixlist[p] = row;
    }
}

// ---------------- fp64 np-exact recheck for flagged rows ----------------
__global__ void k_fixup(const float* __restrict__ eg, const float* __restrict__ wg,
                        const float* __restrict__ rn, const float* __restrict__ wnorm,
                        const int* __restrict__ fixlist, const int* __restrict__ fixcnt,
                        int* __restrict__ idx_ws) {
    __shared__ double xs[D_DIM];
    __shared__ float  redv[256];
    __shared__ int    redi[256];
    const int tid = threadIdx.x;
    const int cnt = *fixcnt;
    for (int j = blockIdx.x; j < cnt; j += gridDim.x) {
        int row = fixlist[j];
        __syncthreads();
        xs[tid] = (double)eg[(size_t)row * D_DIM + tid];
        __syncthreads();
        float An = rn[row];
        float bestv = 3.4e38f;
        int besti = 0;
        #pragma unroll
        for (int kk = 0; kk < 4; ++kk) {
            int k = tid + kk * 256;
            const float4* wr = (const float4*)(wg + (size_t)k * D_DIM);
            double sum = 0.0;
            for (int i = 0; i < D_DIM / 4; ++i) {
                float4 f = wr[i];
                sum += xs[4*i+0] * (double)f.x + xs[4*i+1] * (double)f.y
                     + xs[4*i+2] * (double)f.z + xs[4*i+3] * (double)f.w;
            }
            float m32 = (float)sum;
            float d = np_dist(An, m32, wnorm[k]);
            if (d < bestv) { bestv = d; besti = k; }
        }
        redv[tid] = bestv; redi[tid] = besti;
        __syncthreads();
        for (int st = 128; st > 0; st >>= 1) {
            if (tid < st) {
                float ov = redv[tid + st]; int oi = redi[tid + st];
                if (ov < redv[tid] || (ov == redv[tid] && oi < redi[tid])) {
                    redv[tid] = ov; redi[tid] = oi;
                }
            }
            __syncthreads();
        }
        if (tid == 0) idx_ws[row] = redi[0];
    }
}

// ---------------- gather + STE + loss partials + histogram ----------------
__global__ void k_final(const float* __restrict__ eg, const float* __restrict__ wg,
                        const int* __restrict__ idx_ws, float* __restrict__ qout,
                        float* __restrict__ iout, int* __restrict__ hist,
                        double* __restrict__ partials) {
    const int tid = threadIdx.x;
    const int rowBase = blockIdx.x * 16;
    double acc = 0.0;
    for (int rr = 0; rr < 16; ++rr) {
        int row = rowBase + rr;
        int k = idx_ws[row];
        size_t off = (size_t)row * D_DIM + tid;
        float ev = eg[off];
        float wv = wg[(size_t)k * D_DIM + tid];
        float diff = wv - ev;
        qout[off] = ev + diff;
        acc += (double)(diff * diff);
        if (tid == 0) {
            iout[row] = (float)k;
            atomicAdd(&hist[k], 1);
        }
    }
    __shared__ double red[256];
    red[tid] = acc;
    __syncthreads();
    for (int st = 128; st > 0; st >>= 1) {
        if (tid < st) red[tid] += red[tid + st];
        __syncthreads();
    }
    if (tid == 0) partials[blockIdx.x] = red[0];
}

// ---------------- scalars ----------------
__global__ void k_scalars(const int* __restrict__ hist, const double* __restrict__ partials,
                          float* __restrict__ sout) {
    const int tid = threadIdx.x;
    double s = 0.0;
    for (int j = tid; j < N_ROWS / 16; j += 256) s += partials[j];
    int m = 0;
    for (int j = tid; j < K_CB; j += 256) m = max(m, hist[j]);
    __shared__ double rs[256];
    __shared__ int    rm[256];
    rs[tid] = s; rm[tid] = m;
    __syncthreads();
    for (int st = 128; st > 0; st >>= 1) {
        if (tid < st) { rs[tid] += rs[tid + st]; rm[tid] = max(rm[tid], rm[tid + st]); }
        __syncthreads();
    }
    if (tid == 0) {
        sout[0] = (float)(rs[0] / (double)((size_t)N_ROWS * D_DIM));
        sout[1] = (float)rm[0] / 65536.0f;
    }
}

extern "C" void kernel_launch(void* const* d_in, const int* in_sizes, int n_in,
                              void* d_out, int out_size, void* d_ws, size_t ws_size,
                              hipStream_t stream) {
    const float* e = (const float*)d_in[0];
    const float* w = (const float*)d_in[1];
    float* out  = (float*)d_out;
    float* qout = out;
    float* iout = out + (size_t)N_ROWS * D_DIM;
    float* sout = iout + N_ROWS;

    char* ws = (char*)d_ws;
    float*  rn       = (float*) (ws + OFF_RN);
    float*  wn       = (float*) (ws + OFF_WN);
    int*    fixcnt   = (int*)   (ws + OFF_FIXCNT);
    int*    hist     = (int*)   (ws + OFF_HIST);
    int*    idxp     = (int*)   (ws + OFF_IDX);
    int*    list     = (int*)   (ws + OFF_LIST);
    double* partials = (double*)(ws + OFF_PART);

    // top-2 partials live in the q-region of d_out (overwritten later by k_final)
    // 16 slots x N_ROWS: pbest 4 MB, psec 4 MB, pidx 4 MB  (q-region is 64 MB)
    float* pbest = (float*)d_out;
    float* psec  = pbest + 16 * N_ROWS;
    int*   pidx  = (int*)(psec + 16 * N_ROWS);

    hipMemsetAsync(ws + OFF_FIXCNT, 0, 4352, stream);   // fixcnt + hist

    hipLaunchKernelGGL(k_norms,   dim3(N_ROWS / 256), dim3(256), 0, stream, e, rn, N_ROWS);
    hipLaunchKernelGGL(k_norms,   dim3(K_CB / 256),   dim3(256), 0, stream, w, wn, K_CB);
    hipLaunchKernelGGL(k_dist,    dim3(8, 512),       dim3(256), 0, stream, e, w, rn, wn, pbest, psec, pidx);
    hipLaunchKernelGGL(k_merge,   dim3(N_ROWS / 256), dim3(256), 0, stream, pbest, psec, pidx, idxp, list, fixcnt);
    hipLaunchKernelGGL(k_fixup,   dim3(512),          dim3(256), 0, stream, e, w, rn, wn, list, fixcnt, idxp);
    hipLaunchKernelGGL(k_final,   dim3(N_ROWS / 16),  dim3(256), 0, stream, e, w, idxp, qout, iout, hist, partials);
    hipLaunchKernelGGL(k_scalars, dim3(1),            dim3(256), 0, stream, hist, partials, sout);
}

// Round 5
// 604.699 us; speedup vs baseline: 1.4388x; 1.0195x over previous
//
#include <hip/hip_runtime.h>

typedef __attribute__((ext_vector_type(8))) short short8;
typedef __attribute__((ext_vector_type(4))) short short4v;
typedef __attribute__((ext_vector_type(4))) float floatx4;

#define N_ROWS 65536
#define K_CB   1024
#define D_DIM  256

#define TAU 1.5e-4f
#define LDK 40               // LDS k-stride in shorts (32+8): 16B-aligned, 2-way max conflicts

// ---- primary ws layout (needs 14 MB) ----
#define P_RN     0           // float[65536]
#define P_WN     262144      // float[1024]
#define P_FIXCNT 266240      // int
#define P_HIST   266496      // int[1024]
#define P_IDX    270592      // int[65536]
#define P_LIST   532736      // int[65536]
#define P_PART   794880      // double[4096]
#define P_WFRAG  827392      // short[2*32*1024*8] = 1 MB
#define P_PBEST  2097152     // float[16*65536] = 4 MB
#define P_PSEC   6291456     // 4 MB
#define P_PIDX   10485760    // 4 MB
#define P_NEED   14680064

// ---- fallback (R4, proven, needs 827 KB; partials in d_out) ----
#define F_RN     0
#define F_WN     262144
#define F_FIXCNT 266240
#define F_HIST   266496
#define F_IDX    270592
#define F_LIST   532736
#define F_PART   794880

// ---- numpy pairwise fp32 sum-of-squares emulation (contract off!) ----
__device__ __forceinline__ float pw128_sq(const float4* p) {
#pragma clang fp contract(off)
    float4 q0 = p[0], q1 = p[1];
    float r0 = q0.x * q0.x, r1 = q0.y * q0.y, r2 = q0.z * q0.z, r3 = q0.w * q0.w;
    float r4 = q1.x * q1.x, r5 = q1.y * q1.y, r6 = q1.z * q1.z, r7 = q1.w * q1.w;
    for (int i = 1; i < 16; ++i) {
        float4 u0 = p[2 * i], u1 = p[2 * i + 1];
        r0 = r0 + u0.x * u0.x; r1 = r1 + u0.y * u0.y;
        r2 = r2 + u0.z * u0.z; r3 = r3 + u0.w * u0.w;
        r4 = r4 + u1.x * u1.x; r5 = r5 + u1.y * u1.y;
        r6 = r6 + u1.z * u1.z; r7 = r7 + u1.w * u1.w;
    }
    return ((r0 + r1) + (r2 + r3)) + ((r4 + r5) + (r6 + r7));
}
__device__ __forceinline__ float rownorm_np(const float* row) {
#pragma clang fp contract(off)
    float s0 = pw128_sq((const float4*)row);
    float s1 = pw128_sq((const float4*)(row + 128));
    return s0 + s1;
}
__device__ __forceinline__ float np_dist(float A, float m, float Ck) {
#pragma clang fp contract(off)
    float Bv = 2.0f * m;
    float t  = A - Bv;
    return t + Ck;
}
__device__ __forceinline__ unsigned short bf16_rne(float x) {
    unsigned u = __float_as_uint(x);
    unsigned r = u + 0x7fff + ((u >> 16) & 1);
    return (unsigned short)(r >> 16);
}
__device__ __forceinline__ float bf16_tof(unsigned short h) {
    return __uint_as_float(((unsigned)h) << 16);
}

// ---------------- per-row norms, thread-per-row (w + fallback e) ----------------
__global__ void k_norms(const float* __restrict__ g, float* __restrict__ outp, int nrows) {
    int row = blockIdx.x * blockDim.x + threadIdx.x;
    if (row < nrows) outp[row] = rownorm_np(g + (size_t)row * D_DIM);
}

// ---------------- PRIMARY: coalesced e-norms + hi/lo split (32 rows/block) ----------------
#define PRS 260   // padded row stride (floats): 16B-aligned, breaks bank alias
__global__ __launch_bounds__(256) void k_prep_e(
        const float* __restrict__ eg, float* __restrict__ rn,
        unsigned short* __restrict__ ehi, unsigned short* __restrict__ elo) {
    __shared__ __align__(16) float es[32 * PRS];
    const int tid = threadIdx.x;
    const int rowBase = blockIdx.x * 32;
    // phase 1: coalesced stage 32 rows
    #pragma unroll
    for (int j = 0; j < 8; ++j) {
        int f4 = j * 256 + tid;            // 0..2047 float4s
        int row = f4 >> 6, k4 = f4 & 63;
        float4 v = *(const float4*)(eg + (size_t)(rowBase + row) * D_DIM + k4 * 4);
        *(float4*)&es[row * PRS + k4 * 4] = v;
    }
    __syncthreads();
    // phase 2: np-exact norms (64 threads: row = t>>1, half = t&1)
    if (tid < 64) {
        int row = tid >> 1, half = tid & 1;
        float s = pw128_sq((const float4*)&es[row * PRS + half * 128]);
        float so = __shfl_xor(s, 1, 64);
        if (half == 0) rn[rowBase + row] = s + so;   // s0 + s1, np order
    }
    // phase 3: hi/lo split, coalesced writes
    #pragma unroll
    for (int j = 0; j < 8; ++j) {
        int f4 = j * 256 + tid;
        int row = f4 >> 6, k4 = f4 & 63;
        float4 v = *(const float4*)&es[row * PRS + k4 * 4];
        const float a[4] = {v.x, v.y, v.z, v.w};
        short4v h, l;
        #pragma unroll
        for (int i = 0; i < 4; ++i) {
            unsigned short hh = bf16_rne(a[i]);
            h[i] = (short)hh;
            l[i] = (short)bf16_rne(a[i] - bf16_tof(hh));
        }
        size_t off = (size_t)(rowBase + row) * D_DIM + k4 * 4;
        *(short4v*)(ehi + off) = h;
        *(short4v*)(elo + off) = l;
    }
}

// ---------------- PRIMARY: w -> fragment-layout hi/lo table ----------------
// wfrag[hl][kc][col][j] : offset = ((hl*32 + kc)*1024 + col)*8, kc = k/8, j = k%8
__global__ void k_wsplit(const float* __restrict__ wg, unsigned short* __restrict__ wfrag) {
    int t = blockIdx.x * blockDim.x + threadIdx.x;   // 32768 = 1024 cols * 32 kc
    int col = t >> 5, kc = t & 31;
    const float4* src = (const float4*)(wg + (size_t)col * D_DIM + kc * 8);
    float4 v0 = src[0], v1 = src[1];
    const float a[8] = {v0.x, v0.y, v0.z, v0.w, v1.x, v1.y, v1.z, v1.w};
    short8 h, l;
    #pragma unroll
    for (int i = 0; i < 8; ++i) {
        unsigned short hh = bf16_rne(a[i]);
        h[i] = (short)hh;
        l[i] = (short)bf16_rne(a[i] - bf16_tof(hh));
    }
    *(short8*)(wfrag + ((size_t)(kc)      * 1024 + col) * 8) = h;
    *(short8*)(wfrag + ((size_t)(32 + kc) * 1024 + col) * 8) = l;
}

// ---------------- PRIMARY: MFMA split-3 distance, A via LDS, B via wfrag ----------------
__global__ __launch_bounds__(256) void k_dist_p(
        const unsigned short* __restrict__ ehi, const unsigned short* __restrict__ elo,
        const unsigned short* __restrict__ wfrag,
        const float* __restrict__ rn, const float* __restrict__ wnorm,
        float* __restrict__ pbest, float* __restrict__ psec, int* __restrict__ pidx) {
    __shared__ __align__(16) unsigned short Ah[128 * LDK];
    __shared__ __align__(16) unsigned short Al[128 * LDK];

    const int tid  = threadIdx.x;
    const int lane = tid & 63;
    const int wv   = tid >> 6;
    const int q    = lane >> 4;
    const int m15  = lane & 15;
    const int wm   = wv & 1;
    const int wc   = wv >> 1;
    const int rowBase = blockIdx.y * 128;
    const int colBase = blockIdx.x * 128;

    floatx4 acc[4][4];
    #pragma unroll
    for (int mt = 0; mt < 4; ++mt)
        #pragma unroll
        for (int nt = 0; nt < 4; ++nt)
            acc[mt][nt] = (floatx4){0.f, 0.f, 0.f, 0.f};

    const int srow  = tid >> 1;
    const int shalf = (tid & 1) * 16;

    for (int ic = 0; ic < 8; ++ic) {
        __syncthreads();
        {
            size_t goff = (size_t)(rowBase + srow) * D_DIM + ic * 32 + shalf;
            short8 h0 = *(const short8*)(ehi + goff);
            short8 h1 = *(const short8*)(ehi + goff + 8);
            short8 l0 = *(const short8*)(elo + goff);
            short8 l1 = *(const short8*)(elo + goff + 8);
            int base = srow * LDK + shalf;
            *(short8*)&Ah[base]     = h0;
            *(short8*)&Ah[base + 8] = h1;
            *(short8*)&Al[base]     = l0;
            *(short8*)&Al[base + 8] = l1;
        }
        __syncthreads();

        short8 afh[4], afl[4];
        #pragma unroll
        for (int mt = 0; mt < 4; ++mt) {
            int off = (wm * 64 + mt * 16 + m15) * LDK + q * 8;
            afh[mt] = *(short8*)&Ah[off];
            afl[mt] = *(short8*)&Al[off];
        }
        const int kc = ic * 4 + q;
        #pragma unroll
        for (int nt = 0; nt < 4; ++nt) {
            int col = colBase + wc * 64 + nt * 16 + m15;
            short8 bfh = *(const short8*)(wfrag + ((size_t)(kc)      * 1024 + col) * 8);
            short8 bfl = *(const short8*)(wfrag + ((size_t)(32 + kc) * 1024 + col) * 8);
            #pragma unroll
            for (int mt = 0; mt < 4; ++mt) {
                acc[mt][nt] = __builtin_amdgcn_mfma_f32_16x16x32_bf16(afh[mt], bfh, acc[mt][nt], 0, 0, 0);
                acc[mt][nt] = __builtin_amdgcn_mfma_f32_16x16x32_bf16(afh[mt], bfl, acc[mt][nt], 0, 0, 0);
                acc[mt][nt] = __builtin_amdgcn_mfma_f32_16x16x32_bf16(afl[mt], bfh, acc[mt][nt], 0, 0, 0);
            }
        }
    }

    float wnv[4];
    #pragma unroll
    for (int nt = 0; nt < 4; ++nt)
        wnv[nt] = wnorm[colBase + wc * 64 + nt * 16 + m15];

    const int slot = blockIdx.x * 2 + wc;
    #pragma unroll
    for (int mt = 0; mt < 4; ++mt) {
        #pragma unroll
        for (int r = 0; r < 4; ++r) {
            int rowL = wm * 64 + mt * 16 + q * 4 + r;
            float A = rn[rowBase + rowL];
            float b = 3.4e38f, s = 3.4e38f;
            int ix = 0;
            #pragma unroll
            for (int nt = 0; nt < 4; ++nt) {
                float d = np_dist(A, acc[mt][nt][r], wnv[nt]);
                int k = colBase + wc * 64 + nt * 16 + m15;
                if (d < b)      { s = b; b = d; ix = k; }
                else if (d < s) { s = d; }
            }
            #pragma unroll
            for (int m = 1; m < 16; m <<= 1) {
                float bo = __shfl_xor(b, m, 64);
                float so = __shfl_xor(s, m, 64);
                int   io = __shfl_xor(ix, m, 64);
                float ns = fminf(fminf(s, so), fmaxf(b, bo));
                if (bo < b || (bo == b && io < ix)) { b = bo; ix = io; }
                s = ns;
            }
            if (m15 == 0) {
                int row = rowBase + rowL;
                pbest[slot * N_ROWS + row] = b;
                psec [slot * N_ROWS + row] = s;
                pidx [slot * N_ROWS + row] = ix;
            }
        }
    }
}

// ---------------- FALLBACK: R4 k_dist (convert in kernel) ----------------
__global__ __launch_bounds__(256) void k_dist_fb(
        const float* __restrict__ eg, const float* __restrict__ wg,
        const float* __restrict__ rn, const float* __restrict__ wnorm,
        float* __restrict__ pbest, float* __restrict__ psec, int* __restrict__ pidx) {
    __shared__ __align__(16) unsigned short Ah[128 * LDK];
    __shared__ __align__(16) unsigned short Al[128 * LDK];
    __shared__ __align__(16) unsigned short Bh[128 * LDK];
    __shared__ __align__(16) unsigned short Bl[128 * LDK];

    const int tid  = threadIdx.x;
    const int lane = tid & 63;
    const int wv   = tid >> 6;
    const int q    = lane >> 4;
    const int m15  = lane & 15;
    const int wm   = wv & 1;
    const int wc   = wv >> 1;
    const int rowBase = blockIdx.y * 128;
    const int colBase = blockIdx.x * 128;

    floatx4 acc[4][4];
    #pragma unroll
    for (int mt = 0; mt < 4; ++mt)
        #pragma unroll
        for (int nt = 0; nt < 4; ++nt)
            acc[mt][nt] = (floatx4){0.f, 0.f, 0.f, 0.f};

    const int srow = tid >> 1;
    const int skb  = (tid & 1) * 16;

    for (int ic = 0; ic < 8; ++ic) {
        __syncthreads();
        {
            const float4* ga = (const float4*)(eg + (size_t)(rowBase + srow) * D_DIM + ic * 32 + skb);
            const float4* gb = (const float4*)(wg + (size_t)(colBase + srow) * D_DIM + ic * 32 + skb);
            float4 a0 = ga[0], a1 = ga[1], a2 = ga[2], a3 = ga[3];
            float4 b0 = gb[0], b1 = gb[1], b2 = gb[2], b3 = gb[3];
            unsigned short hbuf[16], lbuf[16];
            const float av[16] = {a0.x,a0.y,a0.z,a0.w, a1.x,a1.y,a1.z,a1.w,
                                  a2.x,a2.y,a2.z,a2.w, a3.x,a3.y,a3.z,a3.w};
            #pragma unroll
            for (int i = 0; i < 16; ++i) {
                unsigned short h = bf16_rne(av[i]);
                hbuf[i] = h;
                lbuf[i] = bf16_rne(av[i] - bf16_tof(h));
            }
            int base = srow * LDK + skb;
            *(short8*)&Ah[base] = *(short8*)&hbuf[0];
            *(short8*)&Ah[base + 8] = *(short8*)&hbuf[8];
            *(short8*)&Al[base] = *(short8*)&lbuf[0];
            *(short8*)&Al[base + 8] = *(short8*)&lbuf[8];
            const float bv[16] = {b0.x,b0.y,b0.z,b0.w, b1.x,b1.y,b1.z,b1.w,
                                  b2.x,b2.y,b2.z,b2.w, b3.x,b3.y,b3.z,b3.w};
            #pragma unroll
            for (int i = 0; i < 16; ++i) {
                unsigned short h = bf16_rne(bv[i]);
                hbuf[i] = h;
                lbuf[i] = bf16_rne(bv[i] - bf16_tof(h));
            }
            *(short8*)&Bh[base] = *(short8*)&hbuf[0];
            *(short8*)&Bh[base + 8] = *(short8*)&hbuf[8];
            *(short8*)&Bl[base] = *(short8*)&lbuf[0];
            *(short8*)&Bl[base + 8] = *(short8*)&lbuf[8];
        }
        __syncthreads();

        short8 afh[4], afl[4];
        #pragma unroll
        for (int mt = 0; mt < 4; ++mt) {
            int off = (wm * 64 + mt * 16 + m15) * LDK + q * 8;
            afh[mt] = *(short8*)&Ah[off];
            afl[mt] = *(short8*)&Al[off];
        }
        #pragma unroll
        for (int nt = 0; nt < 4; ++nt) {
            int off = (wc * 64 + nt * 16 + m15) * LDK + q * 8;
            short8 bfh = *(short8*)&Bh[off];
            short8 bfl = *(short8*)&Bl[off];
            #pragma unroll
            for (int mt = 0; mt < 4; ++mt) {
                acc[mt][nt] = __builtin_amdgcn_mfma_f32_16x16x32_bf16(afh[mt], bfh, acc[mt][nt], 0, 0, 0);
                acc[mt][nt] = __builtin_amdgcn_mfma_f32_16x16x32_bf16(afh[mt], bfl, acc[mt][nt], 0, 0, 0);
                acc[mt][nt] = __builtin_amdgcn_mfma_f32_16x16x32_bf16(afl[mt], bfh, acc[mt][nt], 0, 0, 0);
            }
        }
    }

    float wnv[4];
    #pragma unroll
    for (int nt = 0; nt < 4; ++nt)
        wnv[nt] = wnorm[colBase + wc * 64 + nt * 16 + m15];

    const int slot = blockIdx.x * 2 + wc;
    #pragma unroll
    for (int mt = 0; mt < 4; ++mt) {
        #pragma unroll
        for (int r = 0; r < 4; ++r) {
            int rowL = wm * 64 + mt * 16 + q * 4 + r;
            float A = rn[rowBase + rowL];
            float b = 3.4e38f, s = 3.4e38f;
            int ix = 0;
            #pragma unroll
            for (int nt = 0; nt < 4; ++nt) {
                float d = np_dist(A, acc[mt][nt][r], wnv[nt]);
                int k = colBase + wc * 64 + nt * 16 + m15;
                if (d < b)      { s = b; b = d; ix = k; }
                else if (d < s) { s = d; }
            }
            #pragma unroll
            for (int m = 1; m < 16; m <<= 1) {
                float bo = __shfl_xor(b, m, 64);
                float so = __shfl_xor(s, m, 64);
                int   io = __shfl_xor(ix, m, 64);
                float ns = fminf(fminf(s, so), fmaxf(b, bo));
                if (bo < b || (bo == b && io < ix)) { b = bo; ix = io; }
                s = ns;
            }
            if (m15 == 0) {
                int row = rowBase + rowL;
                pbest[slot * N_ROWS + row] = b;
                psec [slot * N_ROWS + row] = s;
                pidx [slot * N_ROWS + row] = ix;
            }
        }
    }
}

// ---------------- merge 16 per-slot partials, TAU flagging ----------------
__global__ void k_merge(const float* __restrict__ pbest, const float* __restrict__ psec,
                        const int* __restrict__ pidx, int* __restrict__ idx_ws,
                        int* __restrict__ fixlist, int* __restrict__ fixcnt) {
    int row = blockIdx.x * blockDim.x + threadIdx.x;
    float b = 3.4e38f, s = 3.4e38f;
    int ix = 0;
    for (int nb = 0; nb < 16; ++nb) {
        float bo = pbest[nb * N_ROWS + row];
        float so = psec [nb * N_ROWS + row];
        int   io = pidx [nb * N_ROWS + row];
        if (bo < b) { s = fminf(b, so); b = bo; ix = io; }
        else        { s = fminf(s, bo); }
    }
    idx_ws[row] = ix;
    if (s - b < TAU) {
        int p = atomicAdd(fixcnt, 1);
        fixlist[p] = row;
    }
}

// ---------------- fp64 np-exact recheck for flagged rows ----------------
__global__ void k_fixup(const float* __restrict__ eg, const float* __restrict__ wg,
                        const float* __restrict__ rn, const float* __restrict__ wnorm,
                        const int* __restrict__ fixlist, const int* __restrict__ fixcnt,
                        int* __restrict__ idx_ws) {
    __shared__ double xs[D_DIM];
    __shared__ float  redv[256];
    __shared__ int    redi[256];
    const int tid = threadIdx.x;
    const int cnt = *fixcnt;
    for (int j = blockIdx.x; j < cnt; j += gridDim.x) {
        int row = fixlist[j];
        __syncthreads();
        xs[tid] = (double)eg[(size_t)row * D_DIM + tid];
        __syncthreads();
        float An = rn[row];
        float bestv = 3.4e38f;
        int besti = 0;
        #pragma unroll
        for (int kk = 0; kk < 4; ++kk) {
            int k = tid + kk * 256;
            const float4* wr = (const float4*)(wg + (size_t)k * D_DIM);
            double sum = 0.0;
            for (int i = 0; i < D_DIM / 4; ++i) {
                float4 f = wr[i];
                sum += xs[4*i+0] * (double)f.x + xs[4*i+1] * (double)f.y
                     + xs[4*i+2] * (double)f.z + xs[4*i+3] * (double)f.w;
            }
            float m32 = (float)sum;
            float d = np_dist(An, m32, wnorm[k]);
            if (d < bestv) { bestv = d; besti = k; }
        }
        redv[tid] = bestv; redi[tid] = besti;
        __syncthreads();
        for (int st = 128; st > 0; st >>= 1) {
            if (tid < st) {
                float ov = redv[tid + st]; int oi = redi[tid + st];
                if (ov < redv[tid] || (ov == redv[tid] && oi < redi[tid])) {
                    redv[tid] = ov; redi[tid] = oi;
                }
            }
            __syncthreads();
        }
        if (tid == 0) idx_ws[row] = redi[0];
    }
}

// ---------------- gather + STE + loss partials + histogram ----------------
__global__ void k_final(const float* __restrict__ eg, const float* __restrict__ wg,
                        const int* __restrict__ idx_ws, float* __restrict__ qout,
                        float* __restrict__ iout, int* __restrict__ hist,
                        double* __restrict__ partials) {
    const int tid = threadIdx.x;
    const int rowBase = blockIdx.x * 16;
    double acc = 0.0;
    for (int rr = 0; rr < 16; ++rr) {
        int row = rowBase + rr;
        int k = idx_ws[row];
        size_t off = (size_t)row * D_DIM + tid;
        float ev = eg[off];
        float wv = wg[(size_t)k * D_DIM + tid];
        float diff = wv - ev;
        qout[off] = ev + diff;
        acc += (double)(diff * diff);
        if (tid == 0) {
            iout[row] = (float)k;
            atomicAdd(&hist[k], 1);
        }
    }
    __shared__ double red[256];
    red[tid] = acc;
    __syncthreads();
    for (int st = 128; st > 0; st >>= 1) {
        if (tid < st) red[tid] += red[tid + st];
        __syncthreads();
    }
    if (tid == 0) partials[blockIdx.x] = red[0];
}

// ---------------- scalars ----------------
__global__ void k_scalars(const int* __restrict__ hist, const double* __restrict__ partials,
                          float* __restrict__ sout) {
    const int tid = threadIdx.x;
    double s = 0.0;
    for (int j = tid; j < N_ROWS / 16; j += 256) s += partials[j];
    int m = 0;
    for (int j = tid; j < K_CB; j += 256) m = max(m, hist[j]);
    __shared__ double rs[256];
    __shared__ int    rm[256];
    rs[tid] = s; rm[tid] = m;
    __syncthreads();
    for (int st = 128; st > 0; st >>= 1) {
        if (tid < st) { rs[tid] += rs[tid + st]; rm[tid] = max(rm[tid], rm[tid + st]); }
        __syncthreads();
    }
    if (tid == 0) {
        sout[0] = (float)(rs[0] / (double)((size_t)N_ROWS * D_DIM));
        sout[1] = (float)rm[0] / 65536.0f;
    }
}

extern "C" void kernel_launch(void* const* d_in, const int* in_sizes, int n_in,
                              void* d_out, int out_size, void* d_ws, size_t ws_size,
                              hipStream_t stream) {
    const float* e = (const float*)d_in[0];
    const float* w = (const float*)d_in[1];
    float* out  = (float*)d_out;
    float* qout = out;
    float* iout = out + (size_t)N_ROWS * D_DIM;
    float* sout = iout + N_ROWS;
    char* ws = (char*)d_ws;

    if (ws_size >= (size_t)P_NEED) {
        // -------- primary path --------
        float*  rn       = (float*) (ws + P_RN);
        float*  wn       = (float*) (ws + P_WN);
        int*    fixcnt   = (int*)   (ws + P_FIXCNT);
        int*    hist     = (int*)   (ws + P_HIST);
        int*    idxp     = (int*)   (ws + P_IDX);
        int*    list     = (int*)   (ws + P_LIST);
        double* partials = (double*)(ws + P_PART);
        unsigned short* wfrag = (unsigned short*)(ws + P_WFRAG);
        float*  pbest    = (float*) (ws + P_PBEST);
        float*  psec     = (float*) (ws + P_PSEC);
        int*    pidx     = (int*)   (ws + P_PIDX);
        // ehi/elo live in the q-region of d_out (exactly 64 MB), overwritten by k_final
        unsigned short* ehi = (unsigned short*)d_out;
        unsigned short* elo = ehi + (size_t)N_ROWS * D_DIM;

        hipMemsetAsync(ws + P_FIXCNT, 0, 4352, stream);
        hipLaunchKernelGGL(k_prep_e,  dim3(N_ROWS / 32),  dim3(256), 0, stream, e, rn, ehi, elo);
        hipLaunchKernelGGL(k_norms,   dim3(K_CB / 256),   dim3(256), 0, stream, w, wn, K_CB);
        hipLaunchKernelGGL(k_wsplit,  dim3(128),          dim3(256), 0, stream, w, wfrag);
        hipLaunchKernelGGL(k_dist_p,  dim3(8, 512),       dim3(256), 0, stream, ehi, elo, wfrag, rn, wn, pbest, psec, pidx);
        hipLaunchKernelGGL(k_merge,   dim3(N_ROWS / 256), dim3(256), 0, stream, pbest, psec, pidx, idxp, list, fixcnt);
        hipLaunchKernelGGL(k_fixup,   dim3(512),          dim3(256), 0, stream, e, w, rn, wn, list, fixcnt, idxp);
        hipLaunchKernelGGL(k_final,   dim3(N_ROWS / 16),  dim3(256), 0, stream, e, w, idxp, qout, iout, hist, partials);
        hipLaunchKernelGGL(k_scalars, dim3(1),            dim3(256), 0, stream, hist, partials, sout);
    } else {
        // -------- fallback: proven R4 path (partials in d_out) --------
        float*  rn       = (float*) (ws + F_RN);
        float*  wn       = (float*) (ws + F_WN);
        int*    fixcnt   = (int*)   (ws + F_FIXCNT);
        int*    hist     = (int*)   (ws + F_HIST);
        int*    idxp     = (int*)   (ws + F_IDX);
        int*    list     = (int*)   (ws + F_LIST);
        double* partials = (double*)(ws + F_PART);
        float* pbest = (float*)d_out;
        float* psec  = pbest + 16 * N_ROWS;
        int*   pidx  = (int*)(psec + 16 * N_ROWS);

        hipMemsetAsync(ws + F_FIXCNT, 0, 4352, stream);
        hipLaunchKernelGGL(k_norms,   dim3(N_ROWS / 256), dim3(256), 0, stream, e, rn, N_ROWS);
        hipLaunchKernelGGL(k_norms,   dim3(K_CB / 256),   dim3(256), 0, stream, w, wn, K_CB);
        hipLaunchKernelGGL(k_dist_fb, dim3(8, 512),       dim3(256), 0, stream, e, w, rn, wn, pbest, psec, pidx);
        hipLaunchKernelGGL(k_merge,   dim3(N_ROWS / 256), dim3(256), 0, stream, pbest, psec, pidx, idxp, list, fixcnt);
        hipLaunchKernelGGL(k_fixup,   dim3(512),          dim3(256), 0, stream, e, w, rn, wn, list, fixcnt, idxp);
        hipLaunchKernelGGL(k_final,   dim3(N_ROWS / 16),  dim3(256), 0, stream, e, w, idxp, qout, iout, hist, partials);
        hipLaunchKernelGGL(k_scalars, dim3(1),            dim3(256), 0, stream, hist, partials, sout);
    }
}

// Round 6
// 349.197 us; speedup vs baseline: 2.4915x; 1.7317x over previous
//
#include <hip/hip_runtime.h>

typedef __attribute__((ext_vector_type(8))) short short8;
typedef __attribute__((ext_vector_type(4))) float floatx4;

#define N_ROWS 65536
#define K_CB   1024
#define D_DIM  256

#define TAU 1.5e-4f
#define BLINE 520   // shorts per B LDS line (512 data + 8 pad = 1040 B; staggers banks by 4/line)

// ws layout (bytes) — ~1.9 MB, ws_size >= 14 MB proven on this harness
#define OFF_RN     0         // float[65536]
#define OFF_WN     262144    // float[1024]
#define OFF_FIXCNT 266240    // int
#define OFF_HIST   266496    // int[1024]
#define OFF_IDX    270592    // int[65536]
#define OFF_LIST   532736    // int[65536]
#define OFF_PART   794880    // double[4096]
#define OFF_WFRAG  827392    // ushort[2*32*1024*8] = 1 MB

// ---- numpy pairwise fp32 sum-of-squares emulation (contract off!) ----
__device__ __forceinline__ float pw128_sq(const float4* p) {
#pragma clang fp contract(off)
    float4 q0 = p[0], q1 = p[1];
    float r0 = q0.x * q0.x, r1 = q0.y * q0.y, r2 = q0.z * q0.z, r3 = q0.w * q0.w;
    float r4 = q1.x * q1.x, r5 = q1.y * q1.y, r6 = q1.z * q1.z, r7 = q1.w * q1.w;
    for (int i = 1; i < 16; ++i) {
        float4 u0 = p[2 * i], u1 = p[2 * i + 1];
        r0 = r0 + u0.x * u0.x; r1 = r1 + u0.y * u0.y;
        r2 = r2 + u0.z * u0.z; r3 = r3 + u0.w * u0.w;
        r4 = r4 + u1.x * u1.x; r5 = r5 + u1.y * u1.y;
        r6 = r6 + u1.z * u1.z; r7 = r7 + u1.w * u1.w;
    }
    return ((r0 + r1) + (r2 + r3)) + ((r4 + r5) + (r6 + r7));
}
__device__ __forceinline__ float rownorm_np(const float* row) {
#pragma clang fp contract(off)
    float s0 = pw128_sq((const float4*)row);
    float s1 = pw128_sq((const float4*)(row + 128));
    return s0 + s1;
}
__device__ __forceinline__ float np_dist(float A, float m, float Ck) {
#pragma clang fp contract(off)
    float Bv = 2.0f * m;
    float t  = A - Bv;
    return t + Ck;
}
__device__ __forceinline__ unsigned short bf16_rne(float x) {
    unsigned u = __float_as_uint(x);
    unsigned r = u + 0x7fff + ((u >> 16) & 1);
    return (unsigned short)(r >> 16);
}
__device__ __forceinline__ float bf16_tof(unsigned short h) {
    return __uint_as_float(((unsigned)h) << 16);
}

// ---------------- K1: fused prep — e-norms (coalesced) + w-norms + wfrag ----------------
#define PRS 260
__global__ __launch_bounds__(256) void k_prep(
        const float* __restrict__ eg, const float* __restrict__ wg,
        float* __restrict__ rn, float* __restrict__ wn,
        unsigned short* __restrict__ wfrag) {
    __shared__ __align__(16) float es[32 * PRS];
    const int tid = threadIdx.x;
    const int bx  = blockIdx.x;
    if (bx < 2048) {
        // ---- e-norms: 32 rows, LDS-staged coalesced ----
        const int rowBase = bx * 32;
        #pragma unroll
        for (int j = 0; j < 8; ++j) {
            int f4 = j * 256 + tid;
            int row = f4 >> 6, k4 = f4 & 63;
            float4 v = *(const float4*)(eg + (size_t)(rowBase + row) * D_DIM + k4 * 4);
            *(float4*)&es[row * PRS + k4 * 4] = v;
        }
        __syncthreads();
        if (tid < 64) {
            int row = tid >> 1, half = tid & 1;
            float s = pw128_sq((const float4*)&es[row * PRS + half * 128]);
            float so = __shfl_xor(s, 1, 64);
            if (half == 0) rn[rowBase + row] = s + so;
        }
    } else if (bx < 2052) {
        // ---- w-norms: thread-per-row (1024 rows total) ----
        int row = (bx - 2048) * 256 + tid;
        wn[row] = rownorm_np(wg + (size_t)row * D_DIM);
    } else {
        // ---- wfrag: hi/lo split into fragment layout [hl][kc][col][8] ----
        int t = (bx - 2052) * 256 + tid;     // 0..32767
        int col = t >> 5, kc = t & 31;
        const float4* src = (const float4*)(wg + (size_t)col * D_DIM + kc * 8);
        float4 v0 = src[0], v1 = src[1];
        const float a[8] = {v0.x, v0.y, v0.z, v0.w, v1.x, v1.y, v1.z, v1.w};
        short8 h, l;
        #pragma unroll
        for (int i = 0; i < 8; ++i) {
            unsigned short hh = bf16_rne(a[i]);
            h[i] = (short)hh;
            l[i] = (short)bf16_rne(a[i] - bf16_tof(hh));
        }
        *(short8*)(wfrag + ((size_t)(kc)      * 1024 + col) * 8) = h;
        *(short8*)(wfrag + ((size_t)(32 + kc) * 1024 + col) * 8) = l;
    }
}

// ---------------- K2: MFMA split-3 distance — A in registers, full col sweep ----------------
// grid(512): block = 128 rows; wave = 32 rows (2 mt); 16 col-phases of 64 codes
__global__ __launch_bounds__(256, 2) void k_dist(
        const float* __restrict__ eg, const unsigned short* __restrict__ wfrag,
        const float* __restrict__ rn, const float* __restrict__ wn,
        int* __restrict__ idx_ws, int* __restrict__ fixlist, int* __restrict__ fixcnt) {
    __shared__ __align__(16) unsigned short Bs[64 * BLINE];
    const int tid  = threadIdx.x;
    const int lane = tid & 63;
    const int wv   = tid >> 6;
    const int q    = lane >> 4;
    const int m15  = lane & 15;
    const int waveRow = blockIdx.x * 128 + wv * 32;

    // ---- A fragments: load fp32, split hi/lo, keep in registers for whole kernel ----
    short8 afh[2][8], afl[2][8];
    #pragma unroll
    for (int mt = 0; mt < 2; ++mt) {
        const float* rowp = eg + (size_t)(waveRow + mt * 16 + m15) * D_DIM + q * 8;
        #pragma unroll
        for (int win = 0; win < 8; ++win) {
            const float4* pa = (const float4*)(rowp + win * 32);
            float4 x0 = pa[0], x1 = pa[1];
            const float a[8] = {x0.x, x0.y, x0.z, x0.w, x1.x, x1.y, x1.z, x1.w};
            short8 h, l;
            #pragma unroll
            for (int i = 0; i < 8; ++i) {
                unsigned short hh = bf16_rne(a[i]);
                h[i] = (short)hh;
                l[i] = (short)bf16_rne(a[i] - bf16_tof(hh));
            }
            afh[mt][win] = h;
            afl[mt][win] = l;
        }
    }
    // row norms for this lane's 8 C-row slots (row = mt*16 + q*4 + reg)
    float rnv[8];
    #pragma unroll
    for (int mt = 0; mt < 2; ++mt)
        #pragma unroll
        for (int reg = 0; reg < 4; ++reg)
            rnv[mt * 4 + reg] = rn[waveRow + mt * 16 + q * 4 + reg];

    float best[8], sec[8];
    int bidx[8];
    #pragma unroll
    for (int s = 0; s < 8; ++s) { best[s] = 3.4e38f; sec[s] = 3.4e38f; bidx[s] = 0; }

    for (int cb = 0; cb < 16; ++cb) {
        __syncthreads();   // Bs reuse guard
        // stage this phase's B tile: 64 lines of 1 KB via global_load_lds, 16 lines/wave
        #pragma unroll
        for (int t = 0; t < 16; ++t) {
            int L = wv * 16 + t;   // = hl*32 + kc
            const unsigned short* src = wfrag + ((size_t)L * 1024 + cb * 64) * 8 + lane * 8;
            __builtin_amdgcn_global_load_lds(
                (const __attribute__((address_space(1))) unsigned int*)src,
                (__attribute__((address_space(3))) unsigned int*)&Bs[L * BLINE],
                16, 0, 0);
        }
        __syncthreads();   // compiler emits vmcnt(0) drain before barrier

        floatx4 acc[2][4];
        #pragma unroll
        for (int mt = 0; mt < 2; ++mt)
            #pragma unroll
            for (int nt = 0; nt < 4; ++nt)
                acc[mt][nt] = (floatx4){0.f, 0.f, 0.f, 0.f};

        #pragma unroll
        for (int nt = 0; nt < 4; ++nt) {
            #pragma unroll
            for (int win = 0; win < 8; ++win) {
                int kc = win * 4 + q;
                short8 bfh = *(short8*)&Bs[(kc)      * BLINE + (nt * 16 + m15) * 8];
                short8 bfl = *(short8*)&Bs[(32 + kc) * BLINE + (nt * 16 + m15) * 8];
                acc[0][nt] = __builtin_amdgcn_mfma_f32_16x16x32_bf16(afh[0][win], bfh, acc[0][nt], 0, 0, 0);
                acc[0][nt] = __builtin_amdgcn_mfma_f32_16x16x32_bf16(afh[0][win], bfl, acc[0][nt], 0, 0, 0);
                acc[0][nt] = __builtin_amdgcn_mfma_f32_16x16x32_bf16(afl[0][win], bfh, acc[0][nt], 0, 0, 0);
                acc[1][nt] = __builtin_amdgcn_mfma_f32_16x16x32_bf16(afh[1][win], bfh, acc[1][nt], 0, 0, 0);
                acc[1][nt] = __builtin_amdgcn_mfma_f32_16x16x32_bf16(afh[1][win], bfl, acc[1][nt], 0, 0, 0);
                acc[1][nt] = __builtin_amdgcn_mfma_f32_16x16x32_bf16(afl[1][win], bfh, acc[1][nt], 0, 0, 0);
            }
        }
        // fold distances into running top-2 (cols ascend with cb,nt -> first-min kept)
        #pragma unroll
        for (int nt = 0; nt < 4; ++nt) {
            int col = cb * 64 + nt * 16 + m15;
            float Ck = wn[col];
            #pragma unroll
            for (int mt = 0; mt < 2; ++mt)
                #pragma unroll
                for (int reg = 0; reg < 4; ++reg) {
                    int s = mt * 4 + reg;
                    float d = np_dist(rnv[s], acc[mt][nt][reg], Ck);
                    if (d < best[s])     { sec[s] = best[s]; best[s] = d; bidx[s] = col; }
                    else if (d < sec[s]) { sec[s] = d; }
                }
        }
    }

    // butterfly top-2 merge across the 16 m15 lanes (rows live per (q,mt,reg))
    #pragma unroll
    for (int s = 0; s < 8; ++s) {
        float b = best[s], se = sec[s];
        int ix = bidx[s];
        #pragma unroll
        for (int m = 1; m < 16; m <<= 1) {
            float bo = __shfl_xor(b, m, 64);
            float so = __shfl_xor(se, m, 64);
            int   io = __shfl_xor(ix, m, 64);
            float ns = fminf(fminf(se, so), fmaxf(b, bo));
            if (bo < b || (bo == b && io < ix)) { b = bo; ix = io; }
            se = ns;
        }
        if (m15 == 0) {
            int row = waveRow + (s >> 2) * 16 + q * 4 + (s & 3);
            idx_ws[row] = ix;
            if (se - b < TAU) {
                int p = atomicAdd(fixcnt, 1);
                fixlist[p] = row;
            }
        }
    }
}

// ---------------- K3: fp64 np-exact recheck, 4 flagged rows share each w sweep ----------------
__global__ void k_fixup(const float* __restrict__ eg, const float* __restrict__ wg,
                        const float* __restrict__ rn, const float* __restrict__ wnorm,
                        const int* __restrict__ fixlist, const int* __restrict__ fixcnt,
                        int* __restrict__ idx_ws) {
    __shared__ double xs[4][D_DIM];
    __shared__ float  redv[256];
    __shared__ int    redi[256];
    const int tid = threadIdx.x;
    const int cnt = *fixcnt;
    const int ngroups = (cnt + 3) >> 2;
    for (int g = blockIdx.x; g < ngroups; g += gridDim.x) {
        __syncthreads();
        int rows[4];
        #pragma unroll
        for (int i = 0; i < 4; ++i) {
            int j = g * 4 + i;
            rows[i] = fixlist[j < cnt ? j : cnt - 1];
        }
        #pragma unroll
        for (int i = 0; i < 4; ++i)
            xs[i][tid] = (double)eg[(size_t)rows[i] * D_DIM + tid];
        __syncthreads();
        float An[4];
        #pragma unroll
        for (int i = 0; i < 4; ++i) An[i] = rn[rows[i]];
        float bestv[4] = {3.4e38f, 3.4e38f, 3.4e38f, 3.4e38f};
        int   besti[4] = {0, 0, 0, 0};
        #pragma unroll
        for (int kk = 0; kk < 4; ++kk) {
            int k = tid + kk * 256;
            const float4* wr = (const float4*)(wg + (size_t)k * D_DIM);
            double s0 = 0.0, s1 = 0.0, s2 = 0.0, s3 = 0.0;
            for (int i = 0; i < D_DIM / 4; ++i) {
                float4 f = wr[i];
                double f0 = f.x, f1 = f.y, f2 = f.z, f3 = f.w;
                s0 += xs[0][4*i] * f0 + xs[0][4*i+1] * f1 + xs[0][4*i+2] * f2 + xs[0][4*i+3] * f3;
                s1 += xs[1][4*i] * f0 + xs[1][4*i+1] * f1 + xs[1][4*i+2] * f2 + xs[1][4*i+3] * f3;
                s2 += xs[2][4*i] * f0 + xs[2][4*i+1] * f1 + xs[2][4*i+2] * f2 + xs[2][4*i+3] * f3;
                s3 += xs[3][4*i] * f0 + xs[3][4*i+1] * f1 + xs[3][4*i+2] * f2 + xs[3][4*i+3] * f3;
            }
            const double ss[4] = {s0, s1, s2, s3};
            float Cw = wnorm[k];
            #pragma unroll
            for (int i = 0; i < 4; ++i) {
                float d = np_dist(An[i], (float)ss[i], Cw);
                if (d < bestv[i]) { bestv[i] = d; besti[i] = k; }
            }
        }
        #pragma unroll
        for (int i = 0; i < 4; ++i) {
            __syncthreads();
            redv[tid] = bestv[i]; redi[tid] = besti[i];
            __syncthreads();
            for (int st = 128; st > 0; st >>= 1) {
                if (tid < st) {
                    float ov = redv[tid + st]; int oi = redi[tid + st];
                    if (ov < redv[tid] || (ov == redv[tid] && oi < redi[tid])) {
                        redv[tid] = ov; redi[tid] = oi;
                    }
                }
                __syncthreads();
            }
            if (tid == 0 && g * 4 + i < cnt) idx_ws[rows[i]] = redi[0];
        }
    }
}

// ---------------- K4: gather + STE + loss partials + histogram ----------------
__global__ void k_final(const float* __restrict__ eg, const float* __restrict__ wg,
                        const int* __restrict__ idx_ws, float* __restrict__ qout,
                        float* __restrict__ iout, int* __restrict__ hist,
                        double* __restrict__ partials) {
    const int tid = threadIdx.x;
    const int rowBase = blockIdx.x * 16;
    double acc = 0.0;
    for (int rr = 0; rr < 16; ++rr) {
        int row = rowBase + rr;
        int k = idx_ws[row];
        size_t off = (size_t)row * D_DIM + tid;
        float ev = eg[off];
        float wv = wg[(size_t)k * D_DIM + tid];
        float diff = wv - ev;
        qout[off] = ev + diff;
        acc += (double)(diff * diff);
        if (tid == 0) {
            iout[row] = (float)k;
            atomicAdd(&hist[k], 1);
        }
    }
    __shared__ double red[256];
    red[tid] = acc;
    __syncthreads();
    for (int st = 128; st > 0; st >>= 1) {
        if (tid < st) red[tid] += red[tid + st];
        __syncthreads();
    }
    if (tid == 0) partials[blockIdx.x] = red[0];
}

// ---------------- K5: scalars ----------------
__global__ void k_scalars(const int* __restrict__ hist, const double* __restrict__ partials,
                          float* __restrict__ sout) {
    const int tid = threadIdx.x;
    double s = 0.0;
    for (int j = tid; j < N_ROWS / 16; j += 256) s += partials[j];
    int m = 0;
    for (int j = tid; j < K_CB; j += 256) m = max(m, hist[j]);
    __shared__ double rs[256];
    __shared__ int    rm[256];
    rs[tid] = s; rm[tid] = m;
    __syncthreads();
    for (int st = 128; st > 0; st >>= 1) {
        if (tid < st) { rs[tid] += rs[tid + st]; rm[tid] = max(rm[tid], rm[tid + st]); }
        __syncthreads();
    }
    if (tid == 0) {
        sout[0] = (float)(rs[0] / (double)((size_t)N_ROWS * D_DIM));
        sout[1] = (float)rm[0] / 65536.0f;
    }
}

extern "C" void kernel_launch(void* const* d_in, const int* in_sizes, int n_in,
                              void* d_out, int out_size, void* d_ws, size_t ws_size,
                              hipStream_t stream) {
    const float* e = (const float*)d_in[0];
    const float* w = (const float*)d_in[1];
    float* out  = (float*)d_out;
    float* qout = out;
    float* iout = out + (size_t)N_ROWS * D_DIM;
    float* sout = iout + N_ROWS;

    char* ws = (char*)d_ws;
    float*  rn       = (float*) (ws + OFF_RN);
    float*  wn       = (float*) (ws + OFF_WN);
    int*    fixcnt   = (int*)   (ws + OFF_FIXCNT);
    int*    hist     = (int*)   (ws + OFF_HIST);
    int*    idxp     = (int*)   (ws + OFF_IDX);
    int*    list     = (int*)   (ws + OFF_LIST);
    double* partials = (double*)(ws + OFF_PART);
    unsigned short* wfrag = (unsigned short*)(ws + OFF_WFRAG);

    hipMemsetAsync(ws + OFF_FIXCNT, 0, 4352, stream);   // fixcnt + hist

    hipLaunchKernelGGL(k_prep,    dim3(2180),         dim3(256), 0, stream, e, w, rn, wn, wfrag);
    hipLaunchKernelGGL(k_dist,    dim3(512),          dim3(256), 0, stream, e, wfrag, rn, wn, idxp, list, fixcnt);
    hipLaunchKernelGGL(k_fixup,   dim3(512),          dim3(256), 0, stream, e, w, rn, wn, list, fixcnt, idxp);
    hipLaunchKernelGGL(k_final,   dim3(N_ROWS / 16),  dim3(256), 0, stream, e, w, idxp, qout, iout, hist, partials);
    hipLaunchKernelGGL(k_scalars, dim3(1),            dim3(256), 0, stream, hist, partials, sout);
}